// Round 6
// baseline (180.994 us; speedup 1.0000x reference)
//
#include <hip/hip_runtime.h>

typedef unsigned short u16;
typedef unsigned int u32;
typedef _Float16 f16;
typedef __attribute__((ext_vector_type(2))) _Float16 f16x2;
typedef __attribute__((ext_vector_type(4))) _Float16 f16x4;
typedef __attribute__((ext_vector_type(4))) float f32x4;

// Problem constants: B=8, N=256, F=64, C=16, K=2
#define EPSV 1e-4f

// Output element offsets: h_out [0,131072) coord_out [131072,229376) category [229376,1277952)
// Category out-region is scratch: HA[2048*192] | HBJ[8][48][256][4] (f16) until
// the epilogue's copycat blocks overwrite it (only k_edge reads scratch).
// HBJ is K-MAJOR: element (b, j, o') lives at ((b*48 + (o'>>4)*4 + ((o'&15)>>2))*256 + j)*4 + (o'&3)
// so a 16-lane MFMA quad load (consecutive j, fixed o'-quad) is one 128B transaction.

// ---------------- ws layout (fp32 slots) -----------------------------------
// HARD CAP: max offset <= 391872 (round 9 overflow corrupted adjacent alloc).
// f16 tables: slot count = f16_elements / 2 (round 12 aliasing bug).
// REGISTER BUDGET (rounds 2-3 lessons): per-SIMD VGPR pool = 512, unified
// arch+acc. blocks/CU=3 -> 170/wave, 4 -> 128, 5 -> 102 (catastrophic spill).
// Bulk prefetch (R1, 39MB spill, 55.5us) beats JIT loads (R3, 26MB, 66us):
// prefetch > spill-avoidance. R4: rolling 2-deep prefetch + early sagg stash.
// R5: tail fusion. Residual 10.8MB spill is worth only ~2us (0.17us/MB) --
// k_edge plateaued ~49us; (256,3) would cost more in TLP than it saves.
// R6: fuse k_prep_w + k_gemm into k_front (416 blocks). GEMM blocks read
// We1/Wc1/Wqm + biases DIRECTLY (same index map GW1 used) + self-sniff flag,
// so they're independent of prep blocks -> one launch, concurrent execution.
// GW1/B400 regions retired (no readers).
// LDS pads (R2 lesson): sWd stride 20 / sWc2 76 / sWf 20 are REQUIRED;
// trimming to 16/68/16 costs 1.1M bank-conflict cycles for zero occupancy.
static constexpr int WS_FLAG = 0;                     // +16
static constexpr int WS_ATT  = 16;                    // [2048][16]
static constexpr int WS_CT   = 32784;                 // [8][48][256] coord^T fp32
static constexpr int WS_AGG  = 131088;                // [2048][64]
static constexpr int WS_CAC  = 262160;                // [2048][48]  (ends 360464)
static constexpr int WS_GWN1 = 360464;                // f16 [64 o][128 k] = 4096 slots (ends 364560)
static constexpr int WS_GWN2 = 364560;                // f16 [64 f][64 o]  = 2048 slots (ends 366608)
static constexpr int WS_BN1  = 372752;                // [64]
static constexpr int WS_BN2  = 372816;                // [64]
static constexpr int WS_BIAS = 372880;                // be2[64]|bc2[32]|bf1[16]|bf2[16]
static constexpr int WS_GWD  = 373008;                // f16 [192 o'][16 c]   (1536 slots)
static constexpr int WS_GWE2 = 374544;                // f16 [64 f][64 o]     (2048)
static constexpr int WS_GWC2 = 376592;                // f16 [32 mc][64 o]    (1024)
static constexpr int WS_GWF1 = 377616;                // f16 [16][16]         (128)
static constexpr int WS_GWF2 = 377744;                // f16 [16][16]         (128)
// WS_GW1 / WS_B400 retired in R6 (k_gemm reads weights directly).

static __device__ __forceinline__ float bfld(u16 v) {
  return __uint_as_float(((unsigned)v) << 16);
}
static __device__ __forceinline__ u16 f2b(float x) {  // RNE
  unsigned u = __float_as_uint(x);
  u += 0x7FFFu + ((u >> 16) & 1u);
  return (u16)(u >> 16);
}
static __device__ __forceinline__ float ldv(const void* p, int i, int flag) {
  return flag ? bfld(((const u16*)p)[i]) : ((const float*)p)[i];
}
static __device__ __forceinline__ void stv(void* p, int i, float v, int flag) {
  if (flag) ((u16*)p)[i] = f2b(v);
  else      ((float*)p)[i] = v;
}
static __device__ __forceinline__ f16* scratchHA(void* outv, int flag) {
  return (f16*)((char*)outv + (size_t)229376 * (flag ? 2 : 4));
}
static __device__ __forceinline__ int sniff_flag(const void* h) {
  const u16* hu = (const u16*)h;
  int cnt = 0;
  for (int i = 0; i < 128; ++i) {
    unsigned e = (hu[i] >> 7) & 0xFFu;
    if ((e >= 100u && e <= 150u) || hu[i] == 0) ++cnt;
  }
  return (cnt >= 112) ? 1 : 0;
}
static __device__ __forceinline__ f16x4 pack4(float a, float b, float c, float d) {
  const f16x2 lo = __builtin_bit_cast(f16x2, __builtin_amdgcn_cvt_pkrtz(a, b));
  const f16x2 hi = __builtin_bit_cast(f16x2, __builtin_amdgcn_cvt_pkrtz(c, d));
  f16x4 r; r[0] = lo[0]; r[1] = lo[1]; r[2] = hi[0]; r[3] = hi[1]; return r;
}
// pack4 with fused relu: convert-then-max; v_pk_max_f16 (2 ops vs 4 f32 max).
// -0 vs +0 difference is harmless through the following MFMA.
static __device__ __forceinline__ f16x4 pack4_relu(float a, float b, float c, float d) {
  f16x2 lo = __builtin_bit_cast(f16x2, __builtin_amdgcn_cvt_pkrtz(a, b));
  f16x2 hi = __builtin_bit_cast(f16x2, __builtin_amdgcn_cvt_pkrtz(c, d));
  const f16x2 z = {(_Float16)0.f, (_Float16)0.f};
  lo = __builtin_elementwise_max(lo, z);
  hi = __builtin_elementwise_max(hi, z);
  f16x4 r; r[0] = lo[0]; r[1] = lo[1]; r[2] = hi[0]; r[3] = hi[1]; return r;
}
// 48 contiguous input elements -> fp32, vectorized
static __device__ __forceinline__ void load48(const void* p, int node, int flag,
                                              float* dst) {
  if (flag) {
    const uint4* q4 = (const uint4*)((const u16*)p + node * 48);
#pragma unroll
    for (int c = 0; c < 6; ++c) {
      const uint4 v = q4[c];
      const u32 a[4] = {v.x, v.y, v.z, v.w};
#pragma unroll
      for (int e = 0; e < 4; ++e) {
        dst[c * 8 + e * 2]     = bfld((u16)(a[e] & 0xFFFFu));
        dst[c * 8 + e * 2 + 1] = bfld((u16)(a[e] >> 16));
      }
    }
  } else {
    const float4* q4 = (const float4*)((const float*)p + node * 48);
#pragma unroll
    for (int c = 0; c < 12; ++c) {
      const float4 v = q4[c];
      dst[c * 4] = v.x; dst[c * 4 + 1] = v.y; dst[c * 4 + 2] = v.z; dst[c * 4 + 3] = v.w;
    }
  }
}
// stage 64x64 contiguous tile into LDS rows of stride 68, vectorized loads
// (R5: replaces 4096 scalar ldv with 512/1024 vector loads; 8|4 elems stay
// within one 64-col row so no row-crossing).
static __device__ __forceinline__ void stage_h64(const void* h, int hbase, int flag,
                                                 f16* sH, int tid) {
  if (flag) {
    const uint4* src = (const uint4*)((const u16*)h + hbase);  // 8 u16/uint4
    for (int v = tid; v < 512; v += 256) {
      const uint4 x = src[v];
      const int e = v * 8;
      f16* dst = &sH[(e >> 6) * 68 + (e & 63)];
      const u32 a[4] = {x.x, x.y, x.z, x.w};
#pragma unroll
      for (int p = 0; p < 4; ++p) {
        dst[p * 2]     = (f16)bfld((u16)(a[p] & 0xFFFFu));
        dst[p * 2 + 1] = (f16)bfld((u16)(a[p] >> 16));
      }
    }
  } else {
    const float4* src = (const float4*)((const float*)h + hbase);
    for (int v = tid; v < 1024; v += 256) {
      const float4 x = src[v];
      const int e = v * 4;
      f16* dst = &sH[(e >> 6) * 68 + (e & 63)];
      dst[0] = (f16)x.x; dst[1] = (f16)x.y; dst[2] = (f16)x.z; dst[3] = (f16)x.w;
    }
  }
}

// ---------------- K0: fused table-build + layer-1 GEMM (416 x 256) ----------
// blk 0..255: prep (tables for k_edge/k_epi). blk 256..415: layer-1 MFMA GEMM
// -> HA/HBJ/ATT, reading We1/Wc1/Wqm + biases DIRECTLY (no GW1 dependency) and
// self-sniffing the flag, so both halves run concurrently in one launch.
__global__ __launch_bounds__(256) void k_front(
    const void* __restrict__ h, const void* __restrict__ coord,
    const void* __restrict__ We1, const void* __restrict__ Wc1,
    const void* __restrict__ We2, const void* __restrict__ Wc2,
    const void* __restrict__ Wf1, const void* __restrict__ Wf2,
    const void* __restrict__ Wn1, const void* __restrict__ Wn2,
    const void* __restrict__ Wqm,
    const void* __restrict__ be1, const void* __restrict__ bc1,
    const void* __restrict__ bqm, const void* __restrict__ be2,
    const void* __restrict__ bc2, const void* __restrict__ bf1,
    const void* __restrict__ bf2, const void* __restrict__ bn1,
    const void* __restrict__ bn2,
    float* __restrict__ ws, void* __restrict__ outv) {
  const int blk = blockIdx.x, tid = threadIdx.x;
  __shared__ int sflag;
  if (tid == 0) {
    sflag = sniff_flag(h);
    if (blk == 0) ((int*)ws)[WS_FLAG] = sflag;
  }
  __syncthreads();
  const int flag = sflag;

  if (blk < 256) {  // ---------------- prep half ----------------
    const int t = blk * 256 + tid;
    const int STR = 65536;
    // coord^T [b][cd][n]: SOURCE-LINEAR (coalesced reads, scattered writes)
    for (int idx = t; idx < 98304; idx += STR) {
      const int node = idx / 48, cd = idx - node * 48;
      ws[WS_CT + ((node >> 8) * 48 + cd) * 256 + (node & 255)] = ldv(coord, idx, flag);
    }
    f16* gwd  = (f16*)(ws + WS_GWD);
    f16* gwe2 = (f16*)(ws + WS_GWE2);
    f16* gwc2 = (f16*)(ws + WS_GWC2);
    f16* gwf1 = (f16*)(ws + WS_GWF1);
    f16* gwf2 = (f16*)(ws + WS_GWF2);
    for (int idx = t; idx < 3072; idx += STR) {  // [o'][c] <- cols 128..143
      const int o = idx >> 4, c = idx & 15;
      const void* src = (o < 64) ? We1 : Wc1;
      const int row = (o < 64) ? o : (o - 64);
      gwd[idx] = (f16)ldv(src, row * 144 + 128 + c, flag);
    }
    for (int idx = t; idx < 4096; idx += STR) gwe2[idx] = (f16)ldv(We2, idx, flag);
    for (int idx = t; idx < 2048; idx += STR) gwc2[idx] = (f16)ldv(Wc2, idx, flag);
    if (t < 256) { gwf1[t] = (f16)ldv(Wf1, t, flag); gwf2[t] = (f16)ldv(Wf2, t, flag); }
    f16* gwn1 = (f16*)(ws + WS_GWN1);
    f16* gwn2 = (f16*)(ws + WS_GWN2);
    for (int idx = t; idx < 8192; idx += STR) gwn1[idx] = (f16)ldv(Wn1, idx, flag);
    for (int idx = t; idx < 4096; idx += STR) gwn2[idx] = (f16)ldv(Wn2, idx, flag);
    if (t < 64)  ws[WS_BN1 + t] = ldv(bn1, t, flag);
    if (t >= 64 && t < 128) ws[WS_BN2 + t - 64] = ldv(bn2, t - 64, flag);
    if (t >= 128 && t < 192) ws[WS_BIAS + t - 128] = ldv(be2, t - 128, flag);
    if (t >= 192 && t < 224) ws[WS_BIAS + 64 + t - 192] = ldv(bc2, t - 192, flag);
    if (t >= 224 && t < 240) ws[WS_BIAS + 96 + t - 224] = ldv(bf1, t - 224, flag);
    if (t >= 240 && t < 256) ws[WS_BIAS + 112 + t - 240] = ldv(bf2, t - 240, flag);
    return;
  }

  // ---------------- GEMM half (160 blocks) ----------------
  const int gb = blk - 256;
  const int nt = gb / 5, grp = gb % 5;
  const int w = tid >> 6, lane = tid & 63;
  const int q = lane >> 4, l15 = lane & 15;
  f16* HA16 = scratchHA(outv, flag);
  f16* HBJ  = HA16 + 2048 * 192;
  __shared__ __align__(16) f16 sW[80 * 68];
  __shared__ __align__(16) f16 sH[64 * 68];
  __shared__ float sBias[80];
  // direct weight staging: rows grp*80..grp*80+79 of the stacked layer-1
  // matrix [We1(:, :64); Wc1(:, :64); We1(:, 64:128); Wc1(:, 64:128); Wqm]
  for (int idx = tid; idx < 5120; idx += 256) {
    const int r = idx >> 6, k = idx & 63;
    const int row = grp * 80 + r;
    float v;
    if (row < 64)       v = ldv(We1, row * 144 + k, flag);
    else if (row < 192) v = ldv(Wc1, (row - 64) * 144 + k, flag);
    else if (row < 384) {
      const int ro = row - 192;
      v = (ro < 64) ? ldv(We1, ro * 144 + 64 + k, flag)
                    : ldv(Wc1, (ro - 64) * 144 + 64 + k, flag);
    } else              v = ldv(Wqm, (row - 384) * 64 + k, flag);
    sW[r * 68 + k] = (f16)v;
  }
  stage_h64(h, nt * 64 * 64, flag, sH, tid);
  if (tid < 80) {
    const int row = grp * 80 + tid;
    sBias[tid] = (row < 64) ? ldv(be1, row, flag)
               : (row < 192) ? ldv(bc1, row - 64, flag)
               : (row < 384) ? 0.f : ldv(bqm, row - 384, flag);
  }
  __syncthreads();
  f16x4 Af[4];
#pragma unroll
  for (int ks = 0; ks < 4; ++ks)
    Af[ks] = *(const f16x4*)&sH[(w * 16 + l15) * 68 + ks * 16 + q * 4];
#pragma unroll
  for (int ot = 0; ot < 5; ++ot) {
    const float bv = sBias[ot * 16 + l15];
    f32x4 acc = (f32x4){bv, bv, bv, bv};
#pragma unroll
    for (int ks = 0; ks < 4; ++ks) {
      const f16x4 Bf = *(const f16x4*)&sW[(ot * 16 + l15) * 68 + ks * 16 + q * 4];
      acc = __builtin_amdgcn_mfma_f32_16x16x16f16(Af[ks], Bf, acc, 0, 0, 0);
    }
    const int out = grp * 80 + ot * 16 + l15;
    const int nodeD = nt * 64 + w * 16 + q * 4;
#pragma unroll
    for (int r = 0; r < 4; ++r) {
      const int node = nodeD + r;
      if (out < 192) {
        HA16[node * 192 + out] = (f16)acc[r];
      } else if (out < 384) {
        const int ol = out - 192;  // K-major HBJ
        HBJ[(((node >> 8) * 48 + ((ol >> 4) << 2) + ((ol & 15) >> 2)) * 256 +
             (node & 255)) * 4 + (ol & 3)] = (f16)acc[r];
      } else {
        ws[WS_ATT + node * 16 + out - 384] = fmaxf(acc[r], 0.f);
      }
    }
  }
}

// ---------------- K1: MFMA edge kernel (2048 blocks x 256) ------------------
// XCD swizzle (b = blk&7). K-major HBJ. Single staging barrier.
// R1: ft-major phase-1 accumulation (peak acc regs 64->16); bulk prefetch.
// R2 (reverted): 5 blocks/CU + LDS pad trims -> 212MB spill + 1.1M bank conf.
// R3 (reverted): JIT loads -> latency exposed in MFMA chain, slower than R1.
// R4: rolling 2-deep prefetch + sagg stashed to LDS post-butterfly.
// R5: tail fusion (ffv eliminated). Plateau ~49us; residual 10.8MB spill is
// ~2us of upside (0.17us/MB), (256,3) would cost more TLP than it saves.
__global__ __launch_bounds__(256, 4) void k_edge(const void* __restrict__ cat,
                                                 float* __restrict__ ws,
                                                 void* __restrict__ outv) {
  const int node = ((blockIdx.x & 7) << 8) | (blockIdx.x >> 3);
  const int b = node >> 8, i = node & 255;
  const int tid = threadIdx.x;
  const int w = tid >> 6, lane = tid & 63, q = lane >> 4, l15 = lane & 15;
  const int flag = ((const int*)ws)[WS_FLAG];
  const f16* HA16 = scratchHA(outv, flag);
  const f16* HBJ  = HA16 + 2048 * 192;
  const float* __restrict__ cTb = ws + WS_CT + b * 48 * 256;

  __shared__ __align__(16) f16 sWd[192 * 20];
  __shared__ __align__(16) f16 sWe2[64 * 76];
  __shared__ __align__(16) f16 sWc2[32 * 76];
  __shared__ __align__(16) f16 sWf1[16 * 20];
  __shared__ __align__(16) f16 sWf2[16 * 20];
  __shared__ __align__(16) f16 distS[256 * 20];
  __shared__ float sHa[192];
  __shared__ float sB[128];
  __shared__ __align__(16) float red[448];  // [0,256) agg, [256,448) cacc
  // total 36864 B; x4 blocks = 147456 <= 163840 (4 blocks/CU)

  // ---- early address setup + rolling prefetch og0/og1 (no LDS dep) ----
  int jj[4]; float mjt[4];
#pragma unroll
  for (int jt = 0; jt < 4; ++jt) {
    jj[jt] = w * 64 + jt * 16 + l15;
    mjt[jt] = (jj[jt] == i) ? 0.f : 1.f;
  }
  const f16* hbq = HBJ + (size_t)(b * 48 + q) * 1024;  // +og*4096, +j*4
  f16x4 hbA[2][4];
#pragma unroll
  for (int og = 0; og < 2; ++og)
#pragma unroll
    for (int jt = 0; jt < 4; ++jt)
      hbA[og][jt] = *(const f16x4*)(hbq + og * 4096 + jj[jt] * 4);

  {  // stage weight tables
    const u32* gwd = (const u32*)(ws + WS_GWD);
    for (int idx = tid; idx < 1536; idx += 256) {
      const int r = idx >> 3, c = idx & 7;
      *(u32*)&sWd[r * 20 + c * 2] = gwd[idx];
    }
    const u32* gwe = (const u32*)(ws + WS_GWE2);
    for (int idx = tid; idx < 2048; idx += 256) {
      const int r = idx >> 5, c = idx & 31;
      *(u32*)&sWe2[r * 76 + c * 2] = gwe[idx];
    }
    const u32* gwc = (const u32*)(ws + WS_GWC2);
    for (int idx = tid; idx < 1024; idx += 256) {
      const int r = idx >> 5, c = idx & 31;
      *(u32*)&sWc2[r * 76 + c * 2] = gwc[idx];
    }
    if (tid < 128) {
      const int r = tid >> 3, c = tid & 7;
      *(u32*)&sWf1[r * 20 + c * 2] = ((const u32*)(ws + WS_GWF1))[tid];
      *(u32*)&sWf2[r * 20 + c * 2] = ((const u32*)(ws + WS_GWF2))[tid];
    }
    if (tid < 192) sHa[tid] = (float)HA16[node * 192 + tid];
    if (tid < 128) sB[tid] = ws[WS_BIAS + tid];
  }
  {  // distances
    float dr[16];
#pragma unroll
    for (int c = 0; c < 16; ++c) {
      float s = 0.f;
#pragma unroll
      for (int d = 0; d < 3; ++d) {
        const int cd = c * 3 + d;
        const float df = cTb[cd * 256 + i] - cTb[cd * 256 + tid];
        s += df * df;
      }
      dr[c] = sqrtf(s);
    }
#pragma unroll
    for (int kk = 0; kk < 4; ++kk)
      *(f16x4*)&distS[tid * 20 + kk * 4] =
          pack4(dr[4 * kk], dr[4 * kk + 1], dr[4 * kk + 2], dr[4 * kk + 3]);
  }
  __syncthreads();

  f16x4 dfr[4];
#pragma unroll
  for (int jt = 0; jt < 4; ++jt)
    dfr[jt] = *(const f16x4*)&distS[jj[jt] * 20 + q * 4];

  // ---- phase 1a: layer-1 for og 0..3 -> af; rolling 2-deep prefetch ----
  f16x4 af[4][4];
#pragma unroll
  for (int og = 0; og < 4; ++og) {
    const f16x4 wd = *(const f16x4*)&sWd[(og * 16 + l15) * 20 + q * 4];
    const float4 sha = *(const float4*)&sHa[og * 16 + q * 4];
#pragma unroll
    for (int jt = 0; jt < 4; ++jt) {
      const f16x4 hb = hbA[og & 1][jt];
      f32x4 a;
      a[0] = sha.x + (float)hb[0];
      a[1] = sha.y + (float)hb[1];
      a[2] = sha.z + (float)hb[2];
      a[3] = sha.w + (float)hb[3];
      a = __builtin_amdgcn_mfma_f32_16x16x16f16(wd, dfr[jt], a, 0, 0, 0);
      af[og][jt] = pack4_relu(a[0], a[1], a[2], a[3]);
      if (og < 2)  // refill slot with og+2 (1-iteration latency distance)
        hbA[og & 1][jt] = *(const f16x4*)(hbq + (og + 2) * 4096 + jj[jt] * 4);
    }
  }
  // ---- phase 1b: e2 GEMM ft-major; only C2[4] (16 regs) live at a time ----
  float sagg[4][4];
#pragma unroll
  for (int ft = 0; ft < 4; ++ft) {
    f32x4 C2[4];
#pragma unroll
    for (int jt = 0; jt < 4; ++jt) C2[jt] = (f32x4){0.f, 0.f, 0.f, 0.f};
#pragma unroll
    for (int og = 0; og < 4; ++og) {
      const f16x4 we = *(const f16x4*)&sWe2[(ft * 16 + l15) * 76 + og * 16 + q * 4];
#pragma unroll
      for (int jt = 0; jt < 4; ++jt)
        C2[jt] = __builtin_amdgcn_mfma_f32_16x16x16f16(we, af[og][jt], C2[jt], 0, 0, 0);
    }
#pragma unroll
    for (int r = 0; r < 4; ++r) {
      float s = 0.f;
#pragma unroll
      for (int jt = 0; jt < 4; ++jt)
        s += fmaxf(C2[jt][r] + sB[ft * 16 + q * 4 + r], 0.f) * mjt[jt];
      sagg[ft][r] = s;
    }
  }

  // ---- phase-2 rolling prefetch (groups g=0,1 of 8) + cat prefetch.
  // Issued BEFORE the sagg butterfly so ~130 VALU ops hide their latency.
  f16x4 hbB[2][4];
#pragma unroll
  for (int g = 0; g < 2; ++g)
#pragma unroll
    for (int jt = 0; jt < 4; ++jt)
      hbB[g][jt] = *(const f16x4*)(hbq + (4 + g) * 4096 + jj[jt] * 4);
  float cv0[4], cv1[4];
#pragma unroll
  for (int jt = 0; jt < 4; ++jt) {
    if (flag) {
      const u32 p = ((const u32*)cat)[node * 256 + jj[jt]];
      cv0[jt] = bfld((u16)(p & 0xFFFFu));
      cv1[jt] = bfld((u16)(p >> 16));
    } else {
      const float2 p = ((const float2*)cat)[node * 256 + jj[jt]];
      cv0[jt] = p.x; cv1[jt] = p.y;
    }
  }

  // all-reduce butterfly over 16 lanes
#pragma unroll
  for (int ft = 0; ft < 4; ++ft)
#pragma unroll
    for (int st = 1; st < 16; st <<= 1)
#pragma unroll
      for (int r = 0; r < 4; ++r) sagg[ft][r] += __shfl_xor(sagg[ft][r], st, 64);
  // stash sagg now: frees 16 regs for phase 2 (no red reader until barrier)
  if (l15 == 0) {
#pragma unroll
    for (int ft = 0; ft < 4; ++ft)
#pragma unroll
      for (int r = 0; r < 4; ++r) red[w * 64 + ft * 16 + q * 4 + r] = sagg[ft][r];
  }

  // ---- phase 2: category chains -> factors; rolling 2-deep over 8 groups ----
  float fac[4][4] = {};
#pragma unroll
  for (int m = 0; m < 2; ++m) {
    f32x4 C3[4];
#pragma unroll
    for (int jt = 0; jt < 4; ++jt) C3[jt] = (f32x4){0.f, 0.f, 0.f, 0.f};
#pragma unroll
    for (int og2 = 0; og2 < 4; ++og2) {
      const int g = m * 4 + og2;       // flattened group 0..7
      const int og = 4 + g;
      const f16x4 wd = *(const f16x4*)&sWd[(og * 16 + l15) * 20 + q * 4];
      const f16x4 wc = *(const f16x4*)&sWc2[(m * 16 + l15) * 76 + og2 * 16 + q * 4];
      const float4 sha = *(const float4*)&sHa[og * 16 + q * 4];
#pragma unroll
      for (int jt = 0; jt < 4; ++jt) {
        const f16x4 hb = hbB[g & 1][jt];
        f32x4 a;
        a[0] = sha.x + (float)hb[0];
        a[1] = sha.y + (float)hb[1];
        a[2] = sha.z + (float)hb[2];
        a[3] = sha.w + (float)hb[3];
        a = __builtin_amdgcn_mfma_f32_16x16x16f16(wd, dfr[jt], a, 0, 0, 0);
        const f16x4 afv = pack4_relu(a[0], a[1], a[2], a[3]);
        C3[jt] = __builtin_amdgcn_mfma_f32_16x16x16f16(wc, afv, C3[jt], 0, 0, 0);
        if (g < 6)  // refill slot with group g+2 (crosses the m boundary)
          hbB[g & 1][jt] = *(const f16x4*)(hbq + (4 + g + 2) * 4096 + jj[jt] * 4);
      }
    }
#pragma unroll
    for (int jt = 0; jt < 4; ++jt) {
      const float catv = m ? cv1[jt] : cv0[jt];
#pragma unroll
      for (int r = 0; r < 4; ++r)
        fac[jt][r] += catv * fmaxf(C3[jt][r] + sB[64 + m * 16 + q * 4 + r], 0.f);
    }
  }

  // ---- fused tail: factors MLP + coord aggregation per jt (R5) ----
  const f16x4 w1 = *(const f16x4*)&sWf1[l15 * 20 + q * 4];
  const f16x4 w2 = *(const f16x4*)&sWf2[l15 * 20 + q * 4];
  float civ[12];
#pragma unroll
  for (int r = 0; r < 4; ++r)
#pragma unroll
    for (int d = 0; d < 3; ++d) civ[r * 3 + d] = cTb[(3 * (q * 4 + r) + d) * 256 + i];
  float ca[12] = {};
#pragma unroll
  for (int jt = 0; jt < 4; ++jt) {
    const f16x4 fF = pack4(fac[jt][0], fac[jt][1], fac[jt][2], fac[jt][3]);
    const f32x4 z = {0.f, 0.f, 0.f, 0.f};
    f32x4 G = __builtin_amdgcn_mfma_f32_16x16x16f16(w1, fF, z, 0, 0, 0);
    const f16x4 gF = pack4(fmaxf(G[0] + sB[96 + q * 4 + 0], 0.f),
                           fmaxf(G[1] + sB[96 + q * 4 + 1], 0.f),
                           fmaxf(G[2] + sB[96 + q * 4 + 2], 0.f),
                           fmaxf(G[3] + sB[96 + q * 4 + 3], 0.f));
    f32x4 F2 = __builtin_amdgcn_mfma_f32_16x16x16f16(w2, gF, z, 0, 0, 0);
#pragma unroll
    for (int r = 0; r < 4; ++r) {
      const float fv = fmaxf(F2[r] + sB[112 + q * 4 + r], 0.f);
#pragma unroll
      for (int d = 0; d < 3; ++d) {
        const float cj = cTb[(3 * (q * 4 + r) + d) * 256 + jj[jt]];
        ca[r * 3 + d] += fv * (civ[r * 3 + d] - cj);
      }
    }
  }
#pragma unroll
  for (int st = 1; st < 16; st <<= 1)
#pragma unroll
    for (int u = 0; u < 12; ++u) ca[u] += __shfl_xor(ca[u], st, 64);

  if (l15 == 0) {
#pragma unroll
    for (int u = 0; u < 12; ++u) red[256 + w * 48 + q * 12 + u] = ca[u];
  }
  __syncthreads();
  if (tid < 64) {
    ws[WS_AGG + node * 64 + tid] = red[tid] + red[64 + tid] + red[128 + tid] + red[192 + tid];
  } else if (tid < 112) {
    const int u = tid - 64;
    ws[WS_CAC + node * 48 + u] =
        red[256 + u] + red[256 + 48 + u] + red[256 + 96 + u] + red[256 + 144 + u];
  }
}

// ---------------- K2: fused epilogue (552 x 256) ----------------------------
// blk 0..31: node model (MFMA); 32..39: coord pipeline; 40..551: copycat.
__global__ __launch_bounds__(256) void k_epi(const void* __restrict__ h,
                                             const void* __restrict__ coord,
                                             const void* __restrict__ vel,
                                             const void* __restrict__ cat,
                                             const void* __restrict__ Wcv,
                                             const void* __restrict__ Wql,
                                             const void* __restrict__ Wkl,
                                             const float* __restrict__ ws,
                                             void* __restrict__ outv) {
  const int blk = blockIdx.x, tid = threadIdx.x;
  const int flag = ((const int*)ws)[WS_FLAG];
  if (blk < 32) {  // ---- node model: 64 nodes/block, chained MFMA GEMMs ----
    const int w = tid >> 6, lane = tid & 63;
    const int q = lane >> 4, l15 = lane & 15;
    __shared__ __align__(16) f16 sW1[64 * 132];
    __shared__ __align__(16) f16 sW2[64 * 68];
    __shared__ __align__(16) f16 sH[64 * 68];
    __shared__ float sbn[128];
    {
      const u32* g1 = (const u32*)(ws + WS_GWN1);
      for (int idx = tid; idx < 4096; idx += 256) {
        const int o = idx >> 6, c = idx & 63;
        *(u32*)&sW1[o * 132 + c * 2] = g1[idx];
      }
      const u32* g2 = (const u32*)(ws + WS_GWN2);
      for (int idx = tid; idx < 2048; idx += 256) {
        const int o = idx >> 5, c = idx & 31;
        *(u32*)&sW2[o * 68 + c * 2] = g2[idx];
      }
      stage_h64(h, blk * 64 * 64, flag, sH, tid);
      if (tid < 128) sbn[tid] = (tid < 64) ? ws[WS_BN1 + tid] : ws[WS_BN2 + tid - 64];
    }
    __syncthreads();
    const int node = blk * 64 + w * 16 + l15;
    const int lrow = w * 16 + l15;
    f16x4 xB[8];
#pragma unroll
    for (int kt = 0; kt < 4; ++kt)
      xB[kt] = *(const f16x4*)&sH[lrow * 68 + kt * 16 + q * 4];
#pragma unroll
    for (int kt = 0; kt < 4; ++kt) {
      const float* ap = ws + WS_AGG + node * 64 + kt * 16 + q * 4;
      xB[4 + kt] = pack4(ap[0], ap[1], ap[2], ap[3]);
    }
    f16x4 hidB[4];
#pragma unroll
    for (int ot = 0; ot < 4; ++ot) {
      f32x4 acc;
#pragma unroll
      for (int r = 0; r < 4; ++r) acc[r] = sbn[ot * 16 + q * 4 + r];
#pragma unroll
      for (int kt = 0; kt < 8; ++kt) {
        const f16x4 a = *(const f16x4*)&sW1[(ot * 16 + l15) * 132 + kt * 16 + q * 4];
        acc = __builtin_amdgcn_mfma_f32_16x16x16f16(a, xB[kt], acc, 0, 0, 0);
      }
      hidB[ot] = pack4(fmaxf(acc[0], 0.f), fmaxf(acc[1], 0.f),
                       fmaxf(acc[2], 0.f), fmaxf(acc[3], 0.f));
    }
#pragma unroll
    for (int ft = 0; ft < 4; ++ft) {
      const f16x4 hl = *(const f16x4*)&sH[lrow * 68 + ft * 16 + q * 4];
      f32x4 acc;
#pragma unroll
      for (int r = 0; r < 4; ++r) acc[r] = sbn[64 + ft * 16 + q * 4 + r] + (float)hl[r];
#pragma unroll
      for (int ot = 0; ot < 4; ++ot) {
        const f16x4 a = *(const f16x4*)&sW2[(ft * 16 + l15) * 68 + ot * 16 + q * 4];
        acc = __builtin_amdgcn_mfma_f32_16x16x16f16(a, hidB[ot], acc, 0, 0, 0);
      }
#pragma unroll
      for (int r = 0; r < 4; ++r)
        stv(outv, node * 64 + ft * 16 + q * 4 + r, acc[r], flag);
    }
  } else if (blk < 40) {  // ---- coord pipeline, b = blk-32 ----
    const int b = blk - 32;
    const int n = tid, node = b * 256 + n;
    const int wave = n >> 6, lane = n & 63;
    __shared__ float wcv[256], wql[256], wkl[256];
    __shared__ float redm[16];
    wcv[n] = ldv(Wcv, n, flag);
    wql[n] = ldv(Wql, n, flag);
    wkl[n] = ldv(Wkl, n, flag);
    float cf[48];
    load48(coord, node, flag, cf);
    float s0 = 0.f, s1 = 0.f, s2 = 0.f;
#pragma unroll
    for (int c = 0; c < 16; ++c) { s0 += cf[c*3]; s1 += cf[c*3+1]; s2 += cf[c*3+2]; }
    for (int s = 1; s < 64; s <<= 1) {
      s0 += __shfl_xor(s0, s, 64); s1 += __shfl_xor(s1, s, 64); s2 += __shfl_xor(s2, s, 64);
    }
    if (lane == 0) { redm[wave*4] = s0; redm[wave*4+1] = s1; redm[wave*4+2] = s2; }
    __syncthreads();
    const float m0 = (redm[0]+redm[4]+redm[8]+redm[12]) * (1.f/4096.f);
    const float m1 = (redm[1]+redm[5]+redm[9]+redm[13]) * (1.f/4096.f);
    const float m2 = (redm[2]+redm[6]+redm[10]+redm[14]) * (1.f/4096.f);
    __syncthreads();
    float velf[48];
    load48(vel, node, flag, velf);
    float att[16];
    {
      const float4* ap = (const float4*)(ws + WS_ATT + node * 16);
#pragma unroll
      for (int c4 = 0; c4 < 4; ++c4) {
        const float4 v = ap[c4];
        att[c4*4] = v.x; att[c4*4+1] = v.y; att[c4*4+2] = v.z; att[c4*4+3] = v.w;
      }
    }
    float cac[48];
    {
      const float4* cp = (const float4*)(ws + WS_CAC + node * 48);
#pragma unroll
      for (int c4 = 0; c4 < 12; ++c4) {
        const float4 v = cp[c4];
        cac[c4*4] = v.x; cac[c4*4+1] = v.y; cac[c4*4+2] = v.z; cac[c4*4+3] = v.w;
      }
    }
    float c3[48];
#pragma unroll
    for (int c = 0; c < 16; ++c) {
      const float at = att[c];
#pragma unroll
      for (int d = 0; d < 3; ++d) {
        const int cd = c * 3 + d;
        const float md = (d == 0) ? m0 : ((d == 1) ? m1 : m2);
        float cc = at * (cf[cd] - md) + cf[cd];
        cc += cac[cd];
        float a = cc;
#pragma unroll
        for (int cp = 0; cp < 16; ++cp) a += velf[cp * 3 + d] * wcv[c * 16 + cp];
        c3[cd] = a;
      }
    }
    float t0 = 0.f, t1 = 0.f, t2 = 0.f;
#pragma unroll
    for (int c = 0; c < 16; ++c) { t0 += c3[c*3]; t1 += c3[c*3+1]; t2 += c3[c*3+2]; }
    for (int s = 1; s < 64; s <<= 1) {
      t0 += __shfl_xor(t0, s, 64); t1 += __shfl_xor(t1, s, 64); t2 += __shfl_xor(t2, s, 64);
    }
    if (lane == 0) { redm[wave*4] = t0; redm[wave*4+1] = t1; redm[wave*4+2] = t2; }
    __syncthreads();
    const float cm0 = (redm[0]+redm[4]+redm[8]+redm[12]) * (1.f/4096.f);
    const float cm1 = (redm[1]+redm[5]+redm[9]+redm[13]) * (1.f/4096.f);
    const float cm2 = (redm[2]+redm[6]+redm[10]+redm[14]) * (1.f/4096.f);
    float cc[48];
#pragma unroll
    for (int c = 0; c < 16; ++c) {
      cc[c*3]   = c3[c*3]   - cm0;
      cc[c*3+1] = c3[c*3+1] - cm1;
      cc[c*3+2] = c3[c*3+2] - cm2;
    }
#pragma unroll
    for (int o = 0; o < 16; ++o) {
      float qv[3], kv[3];
#pragma unroll
      for (int d = 0; d < 3; ++d) {
        float sq = 0.f, sk = 0.f;
#pragma unroll
        for (int cp = 0; cp < 16; ++cp) {
          sq += cc[cp * 3 + d] * wql[o * 16 + cp];
          sk += cc[cp * 3 + d] * wkl[o * 16 + cp];
        }
        qv[d] = sq; kv[d] = sk;
      }
      const float prod = qv[0]*kv[0] + qv[1]*kv[1] + qv[2]*kv[2];
      const float kns  = kv[0]*kv[0] + kv[1]*kv[1] + kv[2]*kv[2];
      const float wq = prod / (kns + EPSV);
#pragma unroll
      for (int d = 0; d < 3; ++d) {
        const float cmd = (d == 0) ? cm0 : ((d == 1) ? cm1 : cm2);
        const float val = (prod >= 0.f) ? qv[d] : (qv[d] - wq * kv[d]);
        stv(outv, 131072 + node * 48 + o * 3 + d, val + cmd, flag);
      }
    }
  } else {  // ---- category passthrough (overwrites scratch; no reader left) ----
    const int idx = (blk - 40) * 256 + tid;  // 131072 total
    if (flag) {
      ((uint4*)((char*)outv + 458752))[idx] = ((const uint4*)cat)[idx];
    } else {
      ((uint4*)((char*)outv + 917504))[idx] = ((const uint4*)cat)[idx];
      ((uint4*)((char*)outv + 917504))[idx + 131072] = ((const uint4*)cat)[idx + 131072];
    }
  }
}

// ---------------- launch ----------------------------------------------------
extern "C" void kernel_launch(void* const* d_in, const int* in_sizes, int n_in,
                              void* d_out, int out_size, void* d_ws, size_t ws_size,
                              hipStream_t stream) {
  (void)in_sizes; (void)n_in; (void)out_size; (void)ws_size;
  const void* h    = d_in[0];
  const void* coord= d_in[1];
  const void* vel  = d_in[2];
  const void* cat  = d_in[3];
  const void* Wcv  = d_in[4];
  const void* We1  = d_in[5];
  const void* be1  = d_in[6];
  const void* We2  = d_in[7];
  const void* be2  = d_in[8];
  const void* Wc1  = d_in[9];
  const void* bc1  = d_in[10];
  const void* Wc2  = d_in[11];
  const void* bc2  = d_in[12];
  const void* Wf1  = d_in[13];
  const void* bf1v = d_in[14];
  const void* Wf2  = d_in[15];
  const void* bf2v = d_in[16];
  const void* Wn1  = d_in[17];
  const void* bn1  = d_in[18];
  const void* Wn2  = d_in[19];
  const void* bn2  = d_in[20];
  const void* Wql  = d_in[21];
  const void* Wkl  = d_in[22];
  const void* Wqm  = d_in[23];
  const void* bqm  = d_in[24];
  float* ws = (float*)d_ws;

  k_front<<<416, 256, 0, stream>>>(h, coord, We1, Wc1, We2, Wc2, Wf1, Wf2,
                                   Wn1, Wn2, Wqm, be1, bc1, bqm, be2, bc2,
                                   bf1v, bf2v, bn1, bn2, ws, d_out);
  k_edge<<<2048, 256, 0, stream>>>(cat, ws, d_out);
  k_epi<<<552, 256, 0, stream>>>(h, coord, vel, cat, Wcv, Wql, Wkl, ws, d_out);
}

// Round 7
// 172.701 us; speedup vs baseline: 1.0480x; 1.0480x over previous
//
#include <hip/hip_runtime.h>

typedef unsigned short u16;
typedef unsigned int u32;
typedef _Float16 f16;
typedef __attribute__((ext_vector_type(2))) _Float16 f16x2;
typedef __attribute__((ext_vector_type(4))) _Float16 f16x4;
typedef __attribute__((ext_vector_type(4))) float f32x4;

// Problem constants: B=8, N=256, F=64, C=16, K=2
#define EPSV 1e-4f

// Output element offsets: h_out [0,131072) coord_out [131072,229376) category [229376,1277952)
// Category out-region is scratch: HA[2048*192] | HBJ[8][48][256][4] (f16) until
// the epilogue's copycat blocks overwrite it (only k_edge reads scratch).
// HBJ is K-MAJOR: element (b, j, o') lives at ((b*48 + (o'>>4)*4 + ((o'&15)>>2))*256 + j)*4 + (o'&3)
// so a 16-lane MFMA quad load (consecutive j, fixed o'-quad) is one 128B transaction.

// ---------------- ws layout (fp32 slots) -----------------------------------
// HARD CAP: max offset <= 391872 (round 9 overflow corrupted adjacent alloc).
// f16 tables: slot count = f16_elements / 2 (round 12 aliasing bug).
// REGISTER BUDGET (rounds 2-3 lessons): per-SIMD VGPR pool = 512, unified
// arch+acc. blocks/CU=3 -> 170/wave, 4 -> 128, 5 -> 102 (catastrophic spill).
// Bulk prefetch (R1, 39MB spill, 55.5us) beats JIT loads (R3, 26MB, 66us):
// prefetch > spill-avoidance. R4: rolling 2-deep prefetch + early sagg stash.
// R5: tail fusion. Residual 10.8MB spill is worth only ~2us (0.17us/MB).
// R6: k_prep_w + k_gemm fused into k_front (launch-count: neutral).
// R7: all table staging vectorized -- uint4 global reads, uint2 LDS writes
// (rows at strides 20/76/132/68 f16 are only 8B-aligned). f16 tables in ws
// are raw-copied; We1/Wc1/Wqm direct reads keep the dtype convert.
// LDS pads (R2 lesson): sWd stride 20 / sWc2 76 / sWf 20 are REQUIRED;
// trimming to 16/68/16 costs 1.1M bank-conflict cycles for zero occupancy.
static constexpr int WS_FLAG = 0;                     // +16
static constexpr int WS_ATT  = 16;                    // [2048][16]
static constexpr int WS_CT   = 32784;                 // [8][48][256] coord^T fp32
static constexpr int WS_AGG  = 131088;                // [2048][64]
static constexpr int WS_CAC  = 262160;                // [2048][48]  (ends 360464)
static constexpr int WS_GWN1 = 360464;                // f16 [64 o][128 k] = 4096 slots (ends 364560)
static constexpr int WS_GWN2 = 364560;                // f16 [64 f][64 o]  = 2048 slots (ends 366608)
static constexpr int WS_BN1  = 372752;                // [64]
static constexpr int WS_BN2  = 372816;                // [64]
static constexpr int WS_BIAS = 372880;                // be2[64]|bc2[32]|bf1[16]|bf2[16]
static constexpr int WS_GWD  = 373008;                // f16 [192 o'][16 c]   (1536 slots)
static constexpr int WS_GWE2 = 374544;                // f16 [64 f][64 o]     (2048)
static constexpr int WS_GWC2 = 376592;                // f16 [32 mc][64 o]    (1024)
static constexpr int WS_GWF1 = 377616;                // f16 [16][16]         (128)
static constexpr int WS_GWF2 = 377744;                // f16 [16][16]         (128)
// WS_GW1 / WS_B400 retired in R6 (k_front GEMM half reads weights directly).

static __device__ __forceinline__ float bfld(u16 v) {
  return __uint_as_float(((unsigned)v) << 16);
}
static __device__ __forceinline__ u16 f2b(float x) {  // RNE
  unsigned u = __float_as_uint(x);
  u += 0x7FFFu + ((u >> 16) & 1u);
  return (u16)(u >> 16);
}
static __device__ __forceinline__ float ldv(const void* p, int i, int flag) {
  return flag ? bfld(((const u16*)p)[i]) : ((const float*)p)[i];
}
static __device__ __forceinline__ void stv(void* p, int i, float v, int flag) {
  if (flag) ((u16*)p)[i] = f2b(v);
  else      ((float*)p)[i] = v;
}
static __device__ __forceinline__ f16* scratchHA(void* outv, int flag) {
  return (f16*)((char*)outv + (size_t)229376 * (flag ? 2 : 4));
}
static __device__ __forceinline__ int sniff_flag(const void* h) {
  const u16* hu = (const u16*)h;
  int cnt = 0;
  for (int i = 0; i < 128; ++i) {
    unsigned e = (hu[i] >> 7) & 0xFFu;
    if ((e >= 100u && e <= 150u) || hu[i] == 0) ++cnt;
  }
  return (cnt >= 112) ? 1 : 0;
}
static __device__ __forceinline__ f16x4 pack4(float a, float b, float c, float d) {
  const f16x2 lo = __builtin_bit_cast(f16x2, __builtin_amdgcn_cvt_pkrtz(a, b));
  const f16x2 hi = __builtin_bit_cast(f16x2, __builtin_amdgcn_cvt_pkrtz(c, d));
  f16x4 r; r[0] = lo[0]; r[1] = lo[1]; r[2] = hi[0]; r[3] = hi[1]; return r;
}
// pack4 with fused relu: convert-then-max; v_pk_max_f16 (2 ops vs 4 f32 max).
// -0 vs +0 difference is harmless through the following MFMA.
static __device__ __forceinline__ f16x4 pack4_relu(float a, float b, float c, float d) {
  f16x2 lo = __builtin_bit_cast(f16x2, __builtin_amdgcn_cvt_pkrtz(a, b));
  f16x2 hi = __builtin_bit_cast(f16x2, __builtin_amdgcn_cvt_pkrtz(c, d));
  const f16x2 z = {(_Float16)0.f, (_Float16)0.f};
  lo = __builtin_elementwise_max(lo, z);
  hi = __builtin_elementwise_max(hi, z);
  f16x4 r; r[0] = lo[0]; r[1] = lo[1]; r[2] = hi[0]; r[3] = hi[1]; return r;
}
// 16B of f16 table -> LDS as two 8B writes (rows at stride 20/76/132/68 f16
// are only 8B-aligned).
static __device__ __forceinline__ void st8h(f16* dst, uint4 v) {
  uint2 lo; lo.x = v.x; lo.y = v.y;
  uint2 hi; hi.x = v.z; hi.y = v.w;
  *(uint2*)dst = lo;
  *(uint2*)(dst + 4) = hi;
}
// 48 contiguous input elements -> fp32, vectorized
static __device__ __forceinline__ void load48(const void* p, int node, int flag,
                                              float* dst) {
  if (flag) {
    const uint4* q4 = (const uint4*)((const u16*)p + node * 48);
#pragma unroll
    for (int c = 0; c < 6; ++c) {
      const uint4 v = q4[c];
      const u32 a[4] = {v.x, v.y, v.z, v.w};
#pragma unroll
      for (int e = 0; e < 4; ++e) {
        dst[c * 8 + e * 2]     = bfld((u16)(a[e] & 0xFFFFu));
        dst[c * 8 + e * 2 + 1] = bfld((u16)(a[e] >> 16));
      }
    }
  } else {
    const float4* q4 = (const float4*)((const float*)p + node * 48);
#pragma unroll
    for (int c = 0; c < 12; ++c) {
      const float4 v = q4[c];
      dst[c * 4] = v.x; dst[c * 4 + 1] = v.y; dst[c * 4 + 2] = v.z; dst[c * 4 + 3] = v.w;
    }
  }
}
// stage 64x64 contiguous tile into LDS rows of stride 68, vectorized loads
// (R5: replaces 4096 scalar ldv with 512/1024 vector loads; 8|4 elems stay
// within one 64-col row so no row-crossing).
static __device__ __forceinline__ void stage_h64(const void* h, int hbase, int flag,
                                                 f16* sH, int tid) {
  if (flag) {
    const uint4* src = (const uint4*)((const u16*)h + hbase);  // 8 u16/uint4
    for (int v = tid; v < 512; v += 256) {
      const uint4 x = src[v];
      const int e = v * 8;
      f16* dst = &sH[(e >> 6) * 68 + (e & 63)];
      const u32 a[4] = {x.x, x.y, x.z, x.w};
#pragma unroll
      for (int p = 0; p < 4; ++p) {
        dst[p * 2]     = (f16)bfld((u16)(a[p] & 0xFFFFu));
        dst[p * 2 + 1] = (f16)bfld((u16)(a[p] >> 16));
      }
    }
  } else {
    const float4* src = (const float4*)((const float*)h + hbase);
    for (int v = tid; v < 1024; v += 256) {
      const float4 x = src[v];
      const int e = v * 4;
      f16* dst = &sH[(e >> 6) * 68 + (e & 63)];
      dst[0] = (f16)x.x; dst[1] = (f16)x.y; dst[2] = (f16)x.z; dst[3] = (f16)x.w;
    }
  }
}

// ---------------- K0: fused table-build + layer-1 GEMM (416 x 256) ----------
// blk 0..255: prep (tables for k_edge/k_epi). blk 256..415: layer-1 MFMA GEMM
// -> HA/HBJ/ATT, reading We1/Wc1/Wqm + biases DIRECTLY (no GW1 dependency) and
// self-sniffing the flag, so both halves run concurrently in one launch.
__global__ __launch_bounds__(256) void k_front(
    const void* __restrict__ h, const void* __restrict__ coord,
    const void* __restrict__ We1, const void* __restrict__ Wc1,
    const void* __restrict__ We2, const void* __restrict__ Wc2,
    const void* __restrict__ Wf1, const void* __restrict__ Wf2,
    const void* __restrict__ Wn1, const void* __restrict__ Wn2,
    const void* __restrict__ Wqm,
    const void* __restrict__ be1, const void* __restrict__ bc1,
    const void* __restrict__ bqm, const void* __restrict__ be2,
    const void* __restrict__ bc2, const void* __restrict__ bf1,
    const void* __restrict__ bf2, const void* __restrict__ bn1,
    const void* __restrict__ bn2,
    float* __restrict__ ws, void* __restrict__ outv) {
  const int blk = blockIdx.x, tid = threadIdx.x;
  __shared__ int sflag;
  if (tid == 0) {
    sflag = sniff_flag(h);
    if (blk == 0) ((int*)ws)[WS_FLAG] = sflag;
  }
  __syncthreads();
  const int flag = sflag;

  if (blk < 256) {  // ---------------- prep half ----------------
    const int t = blk * 256 + tid;
    const int STR = 65536;
    // coord^T [b][cd][n]: SOURCE-LINEAR (coalesced reads, scattered writes)
    for (int idx = t; idx < 98304; idx += STR) {
      const int node = idx / 48, cd = idx - node * 48;
      ws[WS_CT + ((node >> 8) * 48 + cd) * 256 + (node & 255)] = ldv(coord, idx, flag);
    }
    f16* gwd  = (f16*)(ws + WS_GWD);
    f16* gwe2 = (f16*)(ws + WS_GWE2);
    f16* gwc2 = (f16*)(ws + WS_GWC2);
    f16* gwf1 = (f16*)(ws + WS_GWF1);
    f16* gwf2 = (f16*)(ws + WS_GWF2);
    for (int idx = t; idx < 3072; idx += STR) {  // [o'][c] <- cols 128..143
      const int o = idx >> 4, c = idx & 15;
      const void* src = (o < 64) ? We1 : Wc1;
      const int row = (o < 64) ? o : (o - 64);
      gwd[idx] = (f16)ldv(src, row * 144 + 128 + c, flag);
    }
    for (int idx = t; idx < 4096; idx += STR) gwe2[idx] = (f16)ldv(We2, idx, flag);
    for (int idx = t; idx < 2048; idx += STR) gwc2[idx] = (f16)ldv(Wc2, idx, flag);
    if (t < 256) { gwf1[t] = (f16)ldv(Wf1, t, flag); gwf2[t] = (f16)ldv(Wf2, t, flag); }
    f16* gwn1 = (f16*)(ws + WS_GWN1);
    f16* gwn2 = (f16*)(ws + WS_GWN2);
    for (int idx = t; idx < 8192; idx += STR) gwn1[idx] = (f16)ldv(Wn1, idx, flag);
    for (int idx = t; idx < 4096; idx += STR) gwn2[idx] = (f16)ldv(Wn2, idx, flag);
    if (t < 64)  ws[WS_BN1 + t] = ldv(bn1, t, flag);
    if (t >= 64 && t < 128) ws[WS_BN2 + t - 64] = ldv(bn2, t - 64, flag);
    if (t >= 128 && t < 192) ws[WS_BIAS + t - 128] = ldv(be2, t - 128, flag);
    if (t >= 192 && t < 224) ws[WS_BIAS + 64 + t - 192] = ldv(bc2, t - 192, flag);
    if (t >= 224 && t < 240) ws[WS_BIAS + 96 + t - 224] = ldv(bf1, t - 224, flag);
    if (t >= 240 && t < 256) ws[WS_BIAS + 112 + t - 240] = ldv(bf2, t - 240, flag);
    return;
  }

  // ---------------- GEMM half (160 blocks) ----------------
  const int gb = blk - 256;
  const int nt = gb / 5, grp = gb % 5;
  const int w = tid >> 6, lane = tid & 63;
  const int q = lane >> 4, l15 = lane & 15;
  f16* HA16 = scratchHA(outv, flag);
  f16* HBJ  = HA16 + 2048 * 192;
  __shared__ __align__(16) f16 sW[80 * 68];
  __shared__ __align__(16) f16 sH[64 * 68];
  __shared__ float sBias[80];
  // direct weight staging, VECTORIZED (R7): rows grp*80..+79 of the stacked
  // layer-1 matrix [We1(:,:64); Wc1(:,:64); We1(:,64:128); Wc1(:,64:128); Wqm].
  // All row bases are 16B-aligned (144/64-elem rows).
  if (flag) {
    for (int idx = tid; idx < 640; idx += 256) {   // 80 rows x 8 uint4 (8 bf16)
      const int r = idx >> 3, seg = idx & 7;
      const int row = grp * 80 + r;
      const u16* src;
      if (row < 64)       src = (const u16*)We1 + row * 144;
      else if (row < 192) src = (const u16*)Wc1 + (row - 64) * 144;
      else if (row < 384) {
        const int ro = row - 192;
        src = (ro < 64) ? (const u16*)We1 + ro * 144 + 64
                        : (const u16*)Wc1 + (ro - 64) * 144 + 64;
      } else              src = (const u16*)Wqm + (row - 384) * 64;
      const uint4 v = ((const uint4*)src)[seg];
      const u32 a[4] = {v.x, v.y, v.z, v.w};
      f16* dst = &sW[r * 68 + seg * 8];
#pragma unroll
      for (int p = 0; p < 4; ++p) {
        dst[p * 2]     = (f16)bfld((u16)(a[p] & 0xFFFFu));
        dst[p * 2 + 1] = (f16)bfld((u16)(a[p] >> 16));
      }
    }
  } else {
    for (int idx = tid; idx < 1280; idx += 256) {  // 80 rows x 16 float4
      const int r = idx >> 4, seg = idx & 15;
      const int row = grp * 80 + r;
      const float* src;
      if (row < 64)       src = (const float*)We1 + row * 144;
      else if (row < 192) src = (const float*)Wc1 + (row - 64) * 144;
      else if (row < 384) {
        const int ro = row - 192;
        src = (ro < 64) ? (const float*)We1 + ro * 144 + 64
                        : (const float*)Wc1 + (ro - 64) * 144 + 64;
      } else              src = (const float*)Wqm + (row - 384) * 64;
      const float4 v = ((const float4*)src)[seg];
      f16x4 t; t[0] = (f16)v.x; t[1] = (f16)v.y; t[2] = (f16)v.z; t[3] = (f16)v.w;
      *(f16x4*)&sW[r * 68 + seg * 4] = t;          // byte 136r+8seg: 8-aligned
    }
  }
  stage_h64(h, nt * 64 * 64, flag, sH, tid);
  if (tid < 80) {
    const int row = grp * 80 + tid;
    sBias[tid] = (row < 64) ? ldv(be1, row, flag)
               : (row < 192) ? ldv(bc1, row - 64, flag)
               : (row < 384) ? 0.f : ldv(bqm, row - 384, flag);
  }
  __syncthreads();
  f16x4 Af[4];
#pragma unroll
  for (int ks = 0; ks < 4; ++ks)
    Af[ks] = *(const f16x4*)&sH[(w * 16 + l15) * 68 + ks * 16 + q * 4];
#pragma unroll
  for (int ot = 0; ot < 5; ++ot) {
    const float bv = sBias[ot * 16 + l15];
    f32x4 acc = (f32x4){bv, bv, bv, bv};
#pragma unroll
    for (int ks = 0; ks < 4; ++ks) {
      const f16x4 Bf = *(const f16x4*)&sW[(ot * 16 + l15) * 68 + ks * 16 + q * 4];
      acc = __builtin_amdgcn_mfma_f32_16x16x16f16(Af[ks], Bf, acc, 0, 0, 0);
    }
    const int out = grp * 80 + ot * 16 + l15;
    const int nodeD = nt * 64 + w * 16 + q * 4;
#pragma unroll
    for (int r = 0; r < 4; ++r) {
      const int node = nodeD + r;
      if (out < 192) {
        HA16[node * 192 + out] = (f16)acc[r];
      } else if (out < 384) {
        const int ol = out - 192;  // K-major HBJ
        HBJ[(((node >> 8) * 48 + ((ol >> 4) << 2) + ((ol & 15) >> 2)) * 256 +
             (node & 255)) * 4 + (ol & 3)] = (f16)acc[r];
      } else {
        ws[WS_ATT + node * 16 + out - 384] = fmaxf(acc[r], 0.f);
      }
    }
  }
}

// ---------------- K1: MFMA edge kernel (2048 blocks x 256) ------------------
// XCD swizzle (b = blk&7). K-major HBJ. Single staging barrier.
// R1: ft-major phase-1 accumulation (peak acc regs 64->16); bulk prefetch.
// R2 (reverted): 5 blocks/CU + LDS pad trims -> 212MB spill + 1.1M bank conf.
// R3 (reverted): JIT loads -> latency exposed in MFMA chain, slower than R1.
// R4: rolling 2-deep prefetch + sagg stashed to LDS post-butterfly.
// R5: tail fusion (ffv eliminated). R7: uint4/uint2 staging (insts / 4).
// Plateau ~49us; residual 10.8MB spill ~2us of upside (0.17us/MB).
__global__ __launch_bounds__(256, 4) void k_edge(const void* __restrict__ cat,
                                                 float* __restrict__ ws,
                                                 void* __restrict__ outv) {
  const int node = ((blockIdx.x & 7) << 8) | (blockIdx.x >> 3);
  const int b = node >> 8, i = node & 255;
  const int tid = threadIdx.x;
  const int w = tid >> 6, lane = tid & 63, q = lane >> 4, l15 = lane & 15;
  const int flag = ((const int*)ws)[WS_FLAG];
  const f16* HA16 = scratchHA(outv, flag);
  const f16* HBJ  = HA16 + 2048 * 192;
  const float* __restrict__ cTb = ws + WS_CT + b * 48 * 256;

  __shared__ __align__(16) f16 sWd[192 * 20];
  __shared__ __align__(16) f16 sWe2[64 * 76];
  __shared__ __align__(16) f16 sWc2[32 * 76];
  __shared__ __align__(16) f16 sWf1[16 * 20];
  __shared__ __align__(16) f16 sWf2[16 * 20];
  __shared__ __align__(16) f16 distS[256 * 20];
  __shared__ float sHa[192];
  __shared__ float sB[128];
  __shared__ __align__(16) float red[448];  // [0,256) agg, [256,448) cacc
  // total 36864 B; x4 blocks = 147456 <= 163840 (4 blocks/CU)

  // ---- early address setup + rolling prefetch og0/og1 (no LDS dep) ----
  int jj[4]; float mjt[4];
#pragma unroll
  for (int jt = 0; jt < 4; ++jt) {
    jj[jt] = w * 64 + jt * 16 + l15;
    mjt[jt] = (jj[jt] == i) ? 0.f : 1.f;
  }
  const f16* hbq = HBJ + (size_t)(b * 48 + q) * 1024;  // +og*4096, +j*4
  f16x4 hbA[2][4];
#pragma unroll
  for (int og = 0; og < 2; ++og)
#pragma unroll
    for (int jt = 0; jt < 4; ++jt)
      hbA[og][jt] = *(const f16x4*)(hbq + og * 4096 + jj[jt] * 4);

  {  // stage weight tables (R7: uint4 global reads, uint2 LDS writes)
    const uint4* gwd4 = (const uint4*)(ws + WS_GWD);
    for (int idx = tid; idx < 384; idx += 256) {   // 192 rows x 2 uint4
      const int r = idx >> 1, hf = idx & 1;
      st8h(&sWd[r * 20 + hf * 8], gwd4[idx]);
    }
    const uint4* gwe4 = (const uint4*)(ws + WS_GWE2);
    for (int idx = tid; idx < 512; idx += 256) {   // 64 rows x 8 uint4
      const int r = idx >> 3, c8 = idx & 7;
      st8h(&sWe2[r * 76 + c8 * 8], gwe4[idx]);
    }
    {                                              // sWc2: 32 rows x 8 uint4
      const uint4* gwc4 = (const uint4*)(ws + WS_GWC2);
      const int r = tid >> 3, c8 = tid & 7;
      st8h(&sWc2[r * 76 + c8 * 8], gwc4[tid & 255]);
    }
    if (tid < 64) {                                // sWf1/sWf2: 32 uint4 each
      if (tid < 32) {
        const int r = tid >> 1, hf = tid & 1;
        st8h(&sWf1[r * 20 + hf * 8], ((const uint4*)(ws + WS_GWF1))[tid]);
      } else {
        const int t2 = tid - 32, r = t2 >> 1, hf = t2 & 1;
        st8h(&sWf2[r * 20 + hf * 8], ((const uint4*)(ws + WS_GWF2))[t2]);
      }
    }
    if (tid < 192) sHa[tid] = (float)HA16[node * 192 + tid];
    if (tid < 128) sB[tid] = ws[WS_BIAS + tid];
  }
  {  // distances
    float dr[16];
#pragma unroll
    for (int c = 0; c < 16; ++c) {
      float s = 0.f;
#pragma unroll
      for (int d = 0; d < 3; ++d) {
        const int cd = c * 3 + d;
        const float df = cTb[cd * 256 + i] - cTb[cd * 256 + tid];
        s += df * df;
      }
      dr[c] = sqrtf(s);
    }
#pragma unroll
    for (int kk = 0; kk < 4; ++kk)
      *(f16x4*)&distS[tid * 20 + kk * 4] =
          pack4(dr[4 * kk], dr[4 * kk + 1], dr[4 * kk + 2], dr[4 * kk + 3]);
  }
  __syncthreads();

  f16x4 dfr[4];
#pragma unroll
  for (int jt = 0; jt < 4; ++jt)
    dfr[jt] = *(const f16x4*)&distS[jj[jt] * 20 + q * 4];

  // ---- phase 1a: layer-1 for og 0..3 -> af; rolling 2-deep prefetch ----
  f16x4 af[4][4];
#pragma unroll
  for (int og = 0; og < 4; ++og) {
    const f16x4 wd = *(const f16x4*)&sWd[(og * 16 + l15) * 20 + q * 4];
    const float4 sha = *(const float4*)&sHa[og * 16 + q * 4];
#pragma unroll
    for (int jt = 0; jt < 4; ++jt) {
      const f16x4 hb = hbA[og & 1][jt];
      f32x4 a;
      a[0] = sha.x + (float)hb[0];
      a[1] = sha.y + (float)hb[1];
      a[2] = sha.z + (float)hb[2];
      a[3] = sha.w + (float)hb[3];
      a = __builtin_amdgcn_mfma_f32_16x16x16f16(wd, dfr[jt], a, 0, 0, 0);
      af[og][jt] = pack4_relu(a[0], a[1], a[2], a[3]);
      if (og < 2)  // refill slot with og+2 (1-iteration latency distance)
        hbA[og & 1][jt] = *(const f16x4*)(hbq + (og + 2) * 4096 + jj[jt] * 4);
    }
  }
  // ---- phase 1b: e2 GEMM ft-major; only C2[4] (16 regs) live at a time ----
  float sagg[4][4];
#pragma unroll
  for (int ft = 0; ft < 4; ++ft) {
    f32x4 C2[4];
#pragma unroll
    for (int jt = 0; jt < 4; ++jt) C2[jt] = (f32x4){0.f, 0.f, 0.f, 0.f};
#pragma unroll
    for (int og = 0; og < 4; ++og) {
      const f16x4 we = *(const f16x4*)&sWe2[(ft * 16 + l15) * 76 + og * 16 + q * 4];
#pragma unroll
      for (int jt = 0; jt < 4; ++jt)
        C2[jt] = __builtin_amdgcn_mfma_f32_16x16x16f16(we, af[og][jt], C2[jt], 0, 0, 0);
    }
#pragma unroll
    for (int r = 0; r < 4; ++r) {
      float s = 0.f;
#pragma unroll
      for (int jt = 0; jt < 4; ++jt)
        s += fmaxf(C2[jt][r] + sB[ft * 16 + q * 4 + r], 0.f) * mjt[jt];
      sagg[ft][r] = s;
    }
  }

  // ---- phase-2 rolling prefetch (groups g=0,1 of 8) + cat prefetch.
  // Issued BEFORE the sagg butterfly so ~130 VALU ops hide their latency.
  f16x4 hbB[2][4];
#pragma unroll
  for (int g = 0; g < 2; ++g)
#pragma unroll
    for (int jt = 0; jt < 4; ++jt)
      hbB[g][jt] = *(const f16x4*)(hbq + (4 + g) * 4096 + jj[jt] * 4);
  float cv0[4], cv1[4];
#pragma unroll
  for (int jt = 0; jt < 4; ++jt) {
    if (flag) {
      const u32 p = ((const u32*)cat)[node * 256 + jj[jt]];
      cv0[jt] = bfld((u16)(p & 0xFFFFu));
      cv1[jt] = bfld((u16)(p >> 16));
    } else {
      const float2 p = ((const float2*)cat)[node * 256 + jj[jt]];
      cv0[jt] = p.x; cv1[jt] = p.y;
    }
  }

  // all-reduce butterfly over 16 lanes
#pragma unroll
  for (int ft = 0; ft < 4; ++ft)
#pragma unroll
    for (int st = 1; st < 16; st <<= 1)
#pragma unroll
      for (int r = 0; r < 4; ++r) sagg[ft][r] += __shfl_xor(sagg[ft][r], st, 64);
  // stash sagg now: frees 16 regs for phase 2 (no red reader until barrier)
  if (l15 == 0) {
#pragma unroll
    for (int ft = 0; ft < 4; ++ft)
#pragma unroll
      for (int r = 0; r < 4; ++r) red[w * 64 + ft * 16 + q * 4 + r] = sagg[ft][r];
  }

  // ---- phase 2: category chains -> factors; rolling 2-deep over 8 groups ----
  float fac[4][4] = {};
#pragma unroll
  for (int m = 0; m < 2; ++m) {
    f32x4 C3[4];
#pragma unroll
    for (int jt = 0; jt < 4; ++jt) C3[jt] = (f32x4){0.f, 0.f, 0.f, 0.f};
#pragma unroll
    for (int og2 = 0; og2 < 4; ++og2) {
      const int g = m * 4 + og2;       // flattened group 0..7
      const int og = 4 + g;
      const f16x4 wd = *(const f16x4*)&sWd[(og * 16 + l15) * 20 + q * 4];
      const f16x4 wc = *(const f16x4*)&sWc2[(m * 16 + l15) * 76 + og2 * 16 + q * 4];
      const float4 sha = *(const float4*)&sHa[og * 16 + q * 4];
#pragma unroll
      for (int jt = 0; jt < 4; ++jt) {
        const f16x4 hb = hbB[g & 1][jt];
        f32x4 a;
        a[0] = sha.x + (float)hb[0];
        a[1] = sha.y + (float)hb[1];
        a[2] = sha.z + (float)hb[2];
        a[3] = sha.w + (float)hb[3];
        a = __builtin_amdgcn_mfma_f32_16x16x16f16(wd, dfr[jt], a, 0, 0, 0);
        const f16x4 afv = pack4_relu(a[0], a[1], a[2], a[3]);
        C3[jt] = __builtin_amdgcn_mfma_f32_16x16x16f16(wc, afv, C3[jt], 0, 0, 0);
        if (g < 6)  // refill slot with group g+2 (crosses the m boundary)
          hbB[g & 1][jt] = *(const f16x4*)(hbq + (4 + g + 2) * 4096 + jj[jt] * 4);
      }
    }
#pragma unroll
    for (int jt = 0; jt < 4; ++jt) {
      const float catv = m ? cv1[jt] : cv0[jt];
#pragma unroll
      for (int r = 0; r < 4; ++r)
        fac[jt][r] += catv * fmaxf(C3[jt][r] + sB[64 + m * 16 + q * 4 + r], 0.f);
    }
  }

  // ---- fused tail: factors MLP + coord aggregation per jt (R5) ----
  const f16x4 w1 = *(const f16x4*)&sWf1[l15 * 20 + q * 4];
  const f16x4 w2 = *(const f16x4*)&sWf2[l15 * 20 + q * 4];
  float civ[12];
#pragma unroll
  for (int r = 0; r < 4; ++r)
#pragma unroll
    for (int d = 0; d < 3; ++d) civ[r * 3 + d] = cTb[(3 * (q * 4 + r) + d) * 256 + i];
  float ca[12] = {};
#pragma unroll
  for (int jt = 0; jt < 4; ++jt) {
    const f16x4 fF = pack4(fac[jt][0], fac[jt][1], fac[jt][2], fac[jt][3]);
    const f32x4 z = {0.f, 0.f, 0.f, 0.f};
    f32x4 G = __builtin_amdgcn_mfma_f32_16x16x16f16(w1, fF, z, 0, 0, 0);
    const f16x4 gF = pack4(fmaxf(G[0] + sB[96 + q * 4 + 0], 0.f),
                           fmaxf(G[1] + sB[96 + q * 4 + 1], 0.f),
                           fmaxf(G[2] + sB[96 + q * 4 + 2], 0.f),
                           fmaxf(G[3] + sB[96 + q * 4 + 3], 0.f));
    f32x4 F2 = __builtin_amdgcn_mfma_f32_16x16x16f16(w2, gF, z, 0, 0, 0);
#pragma unroll
    for (int r = 0; r < 4; ++r) {
      const float fv = fmaxf(F2[r] + sB[112 + q * 4 + r], 0.f);
#pragma unroll
      for (int d = 0; d < 3; ++d) {
        const float cj = cTb[(3 * (q * 4 + r) + d) * 256 + jj[jt]];
        ca[r * 3 + d] += fv * (civ[r * 3 + d] - cj);
      }
    }
  }
#pragma unroll
  for (int st = 1; st < 16; st <<= 1)
#pragma unroll
    for (int u = 0; u < 12; ++u) ca[u] += __shfl_xor(ca[u], st, 64);

  if (l15 == 0) {
#pragma unroll
    for (int u = 0; u < 12; ++u) red[256 + w * 48 + q * 12 + u] = ca[u];
  }
  __syncthreads();
  if (tid < 64) {
    ws[WS_AGG + node * 64 + tid] = red[tid] + red[64 + tid] + red[128 + tid] + red[192 + tid];
  } else if (tid < 112) {
    const int u = tid - 64;
    ws[WS_CAC + node * 48 + u] =
        red[256 + u] + red[256 + 48 + u] + red[256 + 96 + u] + red[256 + 144 + u];
  }
}

// ---------------- K2: fused epilogue (552 x 256) ----------------------------
// blk 0..31: node model (MFMA); 32..39: coord pipeline; 40..551: copycat.
__global__ __launch_bounds__(256) void k_epi(const void* __restrict__ h,
                                             const void* __restrict__ coord,
                                             const void* __restrict__ vel,
                                             const void* __restrict__ cat,
                                             const void* __restrict__ Wcv,
                                             const void* __restrict__ Wql,
                                             const void* __restrict__ Wkl,
                                             const float* __restrict__ ws,
                                             void* __restrict__ outv) {
  const int blk = blockIdx.x, tid = threadIdx.x;
  const int flag = ((const int*)ws)[WS_FLAG];
  if (blk < 32) {  // ---- node model: 64 nodes/block, chained MFMA GEMMs ----
    const int w = tid >> 6, lane = tid & 63;
    const int q = lane >> 4, l15 = lane & 15;
    __shared__ __align__(16) f16 sW1[64 * 132];
    __shared__ __align__(16) f16 sW2[64 * 68];
    __shared__ __align__(16) f16 sH[64 * 68];
    __shared__ float sbn[128];
    {
      const uint4* g14 = (const uint4*)(ws + WS_GWN1);   // R7: uint4 staging
      for (int idx = tid; idx < 1024; idx += 256) {      // 64 rows x 16 uint4
        const int o = idx >> 4, c8 = idx & 15;
        st8h(&sW1[o * 132 + c8 * 8], g14[idx]);
      }
      const uint4* g24 = (const uint4*)(ws + WS_GWN2);
      for (int idx = tid; idx < 512; idx += 256) {       // 64 rows x 8 uint4
        const int o = idx >> 3, c8 = idx & 7;
        st8h(&sW2[o * 68 + c8 * 8], g24[idx]);
      }
      stage_h64(h, blk * 64 * 64, flag, sH, tid);
      if (tid < 128) sbn[tid] = (tid < 64) ? ws[WS_BN1 + tid] : ws[WS_BN2 + tid - 64];
    }
    __syncthreads();
    const int node = blk * 64 + w * 16 + l15;
    const int lrow = w * 16 + l15;
    f16x4 xB[8];
#pragma unroll
    for (int kt = 0; kt < 4; ++kt)
      xB[kt] = *(const f16x4*)&sH[lrow * 68 + kt * 16 + q * 4];
#pragma unroll
    for (int kt = 0; kt < 4; ++kt) {
      const float* ap = ws + WS_AGG + node * 64 + kt * 16 + q * 4;
      xB[4 + kt] = pack4(ap[0], ap[1], ap[2], ap[3]);
    }
    f16x4 hidB[4];
#pragma unroll
    for (int ot = 0; ot < 4; ++ot) {
      f32x4 acc;
#pragma unroll
      for (int r = 0; r < 4; ++r) acc[r] = sbn[ot * 16 + q * 4 + r];
#pragma unroll
      for (int kt = 0; kt < 8; ++kt) {
        const f16x4 a = *(const f16x4*)&sW1[(ot * 16 + l15) * 132 + kt * 16 + q * 4];
        acc = __builtin_amdgcn_mfma_f32_16x16x16f16(a, xB[kt], acc, 0, 0, 0);
      }
      hidB[ot] = pack4(fmaxf(acc[0], 0.f), fmaxf(acc[1], 0.f),
                       fmaxf(acc[2], 0.f), fmaxf(acc[3], 0.f));
    }
#pragma unroll
    for (int ft = 0; ft < 4; ++ft) {
      const f16x4 hl = *(const f16x4*)&sH[lrow * 68 + ft * 16 + q * 4];
      f32x4 acc;
#pragma unroll
      for (int r = 0; r < 4; ++r) acc[r] = sbn[64 + ft * 16 + q * 4 + r] + (float)hl[r];
#pragma unroll
      for (int ot = 0; ot < 4; ++ot) {
        const f16x4 a = *(const f16x4*)&sW2[(ft * 16 + l15) * 68 + ot * 16 + q * 4];
        acc = __builtin_amdgcn_mfma_f32_16x16x16f16(a, hidB[ot], acc, 0, 0, 0);
      }
#pragma unroll
      for (int r = 0; r < 4; ++r)
        stv(outv, node * 64 + ft * 16 + q * 4 + r, acc[r], flag);
    }
  } else if (blk < 40) {  // ---- coord pipeline, b = blk-32 ----
    const int b = blk - 32;
    const int n = tid, node = b * 256 + n;
    const int wave = n >> 6, lane = n & 63;
    __shared__ float wcv[256], wql[256], wkl[256];
    __shared__ float redm[16];
    wcv[n] = ldv(Wcv, n, flag);
    wql[n] = ldv(Wql, n, flag);
    wkl[n] = ldv(Wkl, n, flag);
    float cf[48];
    load48(coord, node, flag, cf);
    float s0 = 0.f, s1 = 0.f, s2 = 0.f;
#pragma unroll
    for (int c = 0; c < 16; ++c) { s0 += cf[c*3]; s1 += cf[c*3+1]; s2 += cf[c*3+2]; }
    for (int s = 1; s < 64; s <<= 1) {
      s0 += __shfl_xor(s0, s, 64); s1 += __shfl_xor(s1, s, 64); s2 += __shfl_xor(s2, s, 64);
    }
    if (lane == 0) { redm[wave*4] = s0; redm[wave*4+1] = s1; redm[wave*4+2] = s2; }
    __syncthreads();
    const float m0 = (redm[0]+redm[4]+redm[8]+redm[12]) * (1.f/4096.f);
    const float m1 = (redm[1]+redm[5]+redm[9]+redm[13]) * (1.f/4096.f);
    const float m2 = (redm[2]+redm[6]+redm[10]+redm[14]) * (1.f/4096.f);
    __syncthreads();
    float velf[48];
    load48(vel, node, flag, velf);
    float att[16];
    {
      const float4* ap = (const float4*)(ws + WS_ATT + node * 16);
#pragma unroll
      for (int c4 = 0; c4 < 4; ++c4) {
        const float4 v = ap[c4];
        att[c4*4] = v.x; att[c4*4+1] = v.y; att[c4*4+2] = v.z; att[c4*4+3] = v.w;
      }
    }
    float cac[48];
    {
      const float4* cp = (const float4*)(ws + WS_CAC + node * 48);
#pragma unroll
      for (int c4 = 0; c4 < 12; ++c4) {
        const float4 v = cp[c4];
        cac[c4*4] = v.x; cac[c4*4+1] = v.y; cac[c4*4+2] = v.z; cac[c4*4+3] = v.w;
      }
    }
    float c3[48];
#pragma unroll
    for (int c = 0; c < 16; ++c) {
      const float at = att[c];
#pragma unroll
      for (int d = 0; d < 3; ++d) {
        const int cd = c * 3 + d;
        const float md = (d == 0) ? m0 : ((d == 1) ? m1 : m2);
        float cc = at * (cf[cd] - md) + cf[cd];
        cc += cac[cd];
        float a = cc;
#pragma unroll
        for (int cp = 0; cp < 16; ++cp) a += velf[cp * 3 + d] * wcv[c * 16 + cp];
        c3[cd] = a;
      }
    }
    float t0 = 0.f, t1 = 0.f, t2 = 0.f;
#pragma unroll
    for (int c = 0; c < 16; ++c) { t0 += c3[c*3]; t1 += c3[c*3+1]; t2 += c3[c*3+2]; }
    for (int s = 1; s < 64; s <<= 1) {
      t0 += __shfl_xor(t0, s, 64); t1 += __shfl_xor(t1, s, 64); t2 += __shfl_xor(t2, s, 64);
    }
    if (lane == 0) { redm[wave*4] = t0; redm[wave*4+1] = t1; redm[wave*4+2] = t2; }
    __syncthreads();
    const float cm0 = (redm[0]+redm[4]+redm[8]+redm[12]) * (1.f/4096.f);
    const float cm1 = (redm[1]+redm[5]+redm[9]+redm[13]) * (1.f/4096.f);
    const float cm2 = (redm[2]+redm[6]+redm[10]+redm[14]) * (1.f/4096.f);
    float cc[48];
#pragma unroll
    for (int c = 0; c < 16; ++c) {
      cc[c*3]   = c3[c*3]   - cm0;
      cc[c*3+1] = c3[c*3+1] - cm1;
      cc[c*3+2] = c3[c*3+2] - cm2;
    }
#pragma unroll
    for (int o = 0; o < 16; ++o) {
      float qv[3], kv[3];
#pragma unroll
      for (int d = 0; d < 3; ++d) {
        float sq = 0.f, sk = 0.f;
#pragma unroll
        for (int cp = 0; cp < 16; ++cp) {
          sq += cc[cp * 3 + d] * wql[o * 16 + cp];
          sk += cc[cp * 3 + d] * wkl[o * 16 + cp];
        }
        qv[d] = sq; kv[d] = sk;
      }
      const float prod = qv[0]*kv[0] + qv[1]*kv[1] + qv[2]*kv[2];
      const float kns  = kv[0]*kv[0] + kv[1]*kv[1] + kv[2]*kv[2];
      const float wq = prod / (kns + EPSV);
#pragma unroll
      for (int d = 0; d < 3; ++d) {
        const float cmd = (d == 0) ? cm0 : ((d == 1) ? cm1 : cm2);
        const float val = (prod >= 0.f) ? qv[d] : (qv[d] - wq * kv[d]);
        stv(outv, 131072 + node * 48 + o * 3 + d, val + cmd, flag);
      }
    }
  } else {  // ---- category passthrough (overwrites scratch; no reader left) ----
    const int idx = (blk - 40) * 256 + tid;  // 131072 total
    if (flag) {
      ((uint4*)((char*)outv + 458752))[idx] = ((const uint4*)cat)[idx];
    } else {
      ((uint4*)((char*)outv + 917504))[idx] = ((const uint4*)cat)[idx];
      ((uint4*)((char*)outv + 917504))[idx + 131072] = ((const uint4*)cat)[idx + 131072];
    }
  }
}

// ---------------- launch ----------------------------------------------------
extern "C" void kernel_launch(void* const* d_in, const int* in_sizes, int n_in,
                              void* d_out, int out_size, void* d_ws, size_t ws_size,
                              hipStream_t stream) {
  (void)in_sizes; (void)n_in; (void)out_size; (void)ws_size;
  const void* h    = d_in[0];
  const void* coord= d_in[1];
  const void* vel  = d_in[2];
  const void* cat  = d_in[3];
  const void* Wcv  = d_in[4];
  const void* We1  = d_in[5];
  const void* be1  = d_in[6];
  const void* We2  = d_in[7];
  const void* be2  = d_in[8];
  const void* Wc1  = d_in[9];
  const void* bc1  = d_in[10];
  const void* Wc2  = d_in[11];
  const void* bc2  = d_in[12];
  const void* Wf1  = d_in[13];
  const void* bf1v = d_in[14];
  const void* Wf2  = d_in[15];
  const void* bf2v = d_in[16];
  const void* Wn1  = d_in[17];
  const void* bn1  = d_in[18];
  const void* Wn2  = d_in[19];
  const void* bn2  = d_in[20];
  const void* Wql  = d_in[21];
  const void* Wkl  = d_in[22];
  const void* Wqm  = d_in[23];
  const void* bqm  = d_in[24];
  float* ws = (float*)d_ws;

  k_front<<<416, 256, 0, stream>>>(h, coord, We1, Wc1, We2, Wc2, Wf1, Wf2,
                                   Wn1, Wn2, Wqm, be1, bc1, bqm, be2, bc2,
                                   bf1v, bf2v, bn1, bn2, ws, d_out);
  k_edge<<<2048, 256, 0, stream>>>(cat, ws, d_out);
  k_epi<<<552, 256, 0, stream>>>(h, coord, vel, cat, Wcv, Wql, Wkl, ws, d_out);
}